// Round 7
// baseline (218.935 us; speedup 1.0000x reference)
//
#include <hip/hip_runtime.h>
#include <hip/hip_fp16.h>

#define DIM 64
#define BIN_SHIFT 7
#define BINSZ 128      // nodes per bin
#define MAXBINS 1024   // supports N up to 131072
#define PB 512         // edge-slice blocks for hist/bucket (power of 2)

typedef __attribute__((ext_vector_type(2))) float floatx2;
typedef __attribute__((ext_vector_type(4))) float f32x4;
typedef __attribute__((ext_vector_type(8))) _Float16 f16x8;
typedef __attribute__((ext_vector_type(4))) _Float16 f16x4;

// ---------------- pass 0: zero bintot + pooled output ----------------

__global__ __launch_bounds__(256) void k_zero(int* __restrict__ bintot,
                                              float* __restrict__ out,
                                              int NB, int GD) {
    int i = blockIdx.x * 256 + threadIdx.x;
    if (i < NB) bintot[i] = 0;
    for (int j = i; j < GD; j += gridDim.x * 256) out[j] = 0.f;
}

// ---------------- pass 1: per-block LDS histogram -> global bintot (atomic) ----------------

__global__ __launch_bounds__(256) void k_hist2(const int* __restrict__ dst,
                                               int* __restrict__ bintot, int E, int NB) {
    __shared__ int h[MAXBINS];
    for (int i = threadIdx.x; i < NB; i += 256) h[i] = 0;
    __syncthreads();
    int per = (E + PB - 1) / PB;
    int e0 = blockIdx.x * per;
    int e1 = e0 + per; if (e1 > E) e1 = E;
    for (int e = e0 + (int)threadIdx.x; e < e1; e += 256)
        atomicAdd(&h[dst[e] >> BIN_SHIFT], 1);
    __syncthreads();
    for (int i = threadIdx.x; i < NB; i += 256)
        if (h[i]) atomicAdd(&bintot[i], h[i]);
}

// ---------------- pass 2: single-block shfl scan of bin totals -> binoff, bincur ----------------
// NB <= 1024 = 256 threads x 4 contiguous values; 2 barriers total.

__global__ __launch_bounds__(256) void k_scan782(const int* __restrict__ bintot,
                                                 int* __restrict__ binoff,
                                                 int* __restrict__ bincur, int NB, int E) {
    __shared__ int ws[4];
    int tid = threadIdx.x;
    int j0 = tid * 4;
    int v[4]; int sum = 0;
#pragma unroll
    for (int t = 0; t < 4; ++t) {
        int j = j0 + t;
        int x = (j < NB) ? bintot[j] : 0;
        v[t] = sum; sum += x;
    }
    int lane = tid & 63, wv = tid >> 6;
    int x = sum;
#pragma unroll
    for (int d = 1; d < 64; d <<= 1) {
        int t = __shfl_up(x, d);
        if (lane >= d) x += t;
    }
    if (lane == 63) ws[wv] = x;
    __syncthreads();
    int prefix = 0;
    for (int w = 0; w < wv; ++w) prefix += ws[w];
    int ex = prefix + x - sum;               // exclusive base for this thread's 4
#pragma unroll
    for (int t = 0; t < 4; ++t) {
        int j = j0 + t;
        if (j < NB) { binoff[j] = ex + v[t]; bincur[j] = ex + v[t]; }
    }
    if (tid == 255) binoff[NB] = prefix + x; // == E
}

// ---------------- pass 3: bucket scatter via per-bin atomic range reservation ----------------
// pass A: LDS count of this block's slice; reserve [base, base+cnt) per bin from bincur;
// pass B: scatter with LDS cursors. Intra-bin order is arbitrary (binsort re-sorts).

__global__ __launch_bounds__(256) void k_bucket2(const int* __restrict__ src,
                                                 const int* __restrict__ dst,
                                                 int* __restrict__ bincur,
                                                 int* __restrict__ bkt, int E, int NB) {
    __shared__ int cnt_[MAXBINS], base_[MAXBINS];
    int tid = threadIdx.x;
    for (int i = tid; i < NB; i += 256) cnt_[i] = 0;
    __syncthreads();
    int per = (E + PB - 1) / PB;
    int e0 = blockIdx.x * per;
    int e1 = e0 + per; if (e1 > E) e1 = E;
    for (int e = e0 + tid; e < e1; e += 256)
        atomicAdd(&cnt_[dst[e] >> BIN_SHIFT], 1);
    __syncthreads();
    for (int i = tid; i < NB; i += 256) {
        int c = cnt_[i];
        base_[i] = c ? atomicAdd(&bincur[i], c) : 0;
        cnt_[i] = 0;
    }
    __syncthreads();
    for (int e = e0 + tid; e < e1; e += 256) {
        int d = dst[e];
        int b = d >> BIN_SHIFT;
        int pos = base_[b] + atomicAdd(&cnt_[b], 1);
        bkt[pos] = src[e] | ((d & (BINSZ - 1)) << 24);
    }
}

// ---------------- pass 4: per-bin counting sort (shfl scan) -> csr, off, dinv; + gbound ----------------

__global__ __launch_bounds__(256) void k_binsort(const int* __restrict__ bkt,
                                                 const int* __restrict__ binoff,
                                                 int* __restrict__ csr,
                                                 int* __restrict__ off,
                                                 float* __restrict__ dinv,
                                                 const int* __restrict__ batch,
                                                 int* __restrict__ goff,
                                                 int N, int G, int E, int NB) {
    __shared__ int cnt[BINSZ], bas[BINSZ], cur[BINSZ];
    __shared__ int wsum[4];
    int tid = threadIdx.x;
    int b = blockIdx.x;
    int s0 = binoff[b];
    int s1 = binoff[b + 1];
    if (tid < BINSZ) { cnt[tid] = 0; cur[tid] = 0; }
    __syncthreads();
    for (int i = s0 + tid; i < s1; i += 256)
        atomicAdd(&cnt[(bkt[i] >> 24) & (BINSZ - 1)], 1);
    __syncthreads();
    int my = (tid < BINSZ) ? cnt[tid] : 0;
    int lane = tid & 63, wv = tid >> 6;
    int x = my;
#pragma unroll
    for (int d = 1; d < 64; d <<= 1) {
        int t = __shfl_up(x, d);
        if (lane >= d) x += t;
    }
    if (lane == 63) wsum[wv] = x;
    __syncthreads();
    int prefix = 0;
    for (int w = 0; w < wv; ++w) prefix += wsum[w];
    int ex = x + prefix - my;               // exclusive base
    if (tid < BINSZ) {
        bas[tid] = ex;
        int v = (b << BIN_SHIFT) + tid;
        if (v < N) {
            off[v] = s0 + ex;
            dinv[v] = rsqrtf((float)(my + 1));   // +1 self-loop
            if (v == N - 1) off[N] = E;
            // fused gbound (batch sorted)
            int bb = batch[v];
            int prev = (v == 0) ? -1 : batch[v - 1];
            for (int g = prev + 1; g <= bb; ++g) goff[g] = v;
            if (v == N - 1)
                for (int g = bb + 1; g <= G; ++g) goff[g] = N;
        }
    }
    __syncthreads();
    for (int i = s0 + tid; i < s1; i += 256) {
        int p = bkt[i];
        int lo = (p >> 24) & (BINSZ - 1);
        int li = atomicAdd(&cur[lo], 1);
        csr[s0 + bas[lo] + li] = p & 0xFFFFFF;
    }
}

// ---------------- skinny GEMM via MFMA: hs[row] = (X[row] @ W) * dinv[row], fp8 out ----------------
// Wave w computes the 16-row x 16-col tile at cols [16w,16w+16).
// k-map bijection: k = 32s + 8*(lane>>4) + elem, applied to BOTH A and B fragments.
// D layout (HW-verified): col = lane&15, row = 4*(lane>>4) + reg.

__global__ __launch_bounds__(256) void k_gemm(const float* __restrict__ X,
                                              const float* __restrict__ W,
                                              const float* __restrict__ dinv,
                                              unsigned int* __restrict__ Y8, int N) {
    __shared__ float Os[16 * 68];
    int tid = threadIdx.x;
    int lane = tid & 63, w = tid >> 6;
    int m = lane & 15, g = lane >> 4;
    int row0 = blockIdx.x * 16;
    int row = row0 + m;

    // B fragments from global W (row-major [k][n]); L1-hot
    f16x8 B0, B1;
    {
        int n = (w << 4) + m;
        const float* wp = W + (g << 3) * 64 + n;
#pragma unroll
        for (int j = 0; j < 8; ++j) B0[j] = (_Float16)wp[j * 64];
        wp += 32 * 64;
#pragma unroll
        for (int j = 0; j < 8; ++j) B1[j] = (_Float16)wp[j * 64];
    }
    // A fragments straight from global X
    f16x8 A0, A1;
    {
        float4 u0 = make_float4(0.f, 0.f, 0.f, 0.f), u1 = u0, u2 = u0, u3 = u0;
        if (row < N) {
            const float* xp = X + (size_t)row * DIM + (g << 3);
            u0 = *(const float4*)(xp);
            u1 = *(const float4*)(xp + 4);
            u2 = *(const float4*)(xp + 32);
            u3 = *(const float4*)(xp + 36);
        }
        A0[0] = (_Float16)u0.x; A0[1] = (_Float16)u0.y; A0[2] = (_Float16)u0.z; A0[3] = (_Float16)u0.w;
        A0[4] = (_Float16)u1.x; A0[5] = (_Float16)u1.y; A0[6] = (_Float16)u1.z; A0[7] = (_Float16)u1.w;
        A1[0] = (_Float16)u2.x; A1[1] = (_Float16)u2.y; A1[2] = (_Float16)u2.z; A1[3] = (_Float16)u2.w;
        A1[4] = (_Float16)u3.x; A1[5] = (_Float16)u3.y; A1[6] = (_Float16)u3.z; A1[7] = (_Float16)u3.w;
    }
    f32x4 acc = {0.f, 0.f, 0.f, 0.f};
    acc = __builtin_amdgcn_mfma_f32_16x16x32_f16(A0, B0, acc, 0, 0, 0);
    acc = __builtin_amdgcn_mfma_f32_16x16x32_f16(A1, B1, acc, 0, 0, 0);
#pragma unroll
    for (int j = 0; j < 4; ++j)
        Os[((g << 2) + j) * 68 + (w << 4) + m] = acc[j];
    __syncthreads();

    int r = tid >> 4, c = tid & 15;
    int orow = row0 + r;
    if (orow < N) {
        float4 o = *(const float4*)(Os + r * 68 + (c << 2));
        float s = dinv[orow];
        int p = 0;
        p = __builtin_amdgcn_cvt_pk_fp8_f32(o.x * s, o.y * s, p, false);
        p = __builtin_amdgcn_cvt_pk_fp8_f32(o.z * s, o.w * s, p, true);
        Y8[(size_t)orow * 16 + c] = (unsigned int)p;
    } else if (orow == N) {
        Y8[(size_t)orow * 16 + c] = 0u;   // +0 in e4m3 (gather pad row)
    }
}

// ---------------- gather core: 16-lane group per node, 16 edges / 16 loads in flight ----------------
// lane l owns cols 4l..4l+3 (one uint of the fp8 row). Padding slots read row N (zeros,
// single broadcast cacheline). All 16 loads issued before any conversion.

__device__ __forceinline__ float4 gather_rows(const unsigned int* __restrict__ hs8,
                                              const int* __restrict__ csr,
                                              int k0, int k1, int v, int l, int gw4,
                                              int N) {
    float4 a0, a1, a2, a3;
    {
        unsigned int u = hs8[(unsigned)((v << 4) | l)];    // self-loop term
        floatx2 f0 = __builtin_amdgcn_cvt_pk_f32_fp8((int)u, false);
        floatx2 f1 = __builtin_amdgcn_cvt_pk_f32_fp8((int)u, true);
        a0 = make_float4(f0.x, f0.y, f1.x, f1.y);
        a1 = make_float4(0.f, 0.f, 0.f, 0.f);
        a2 = make_float4(0.f, 0.f, 0.f, 0.f);
        a3 = make_float4(0.f, 0.f, 0.f, 0.f);
    }
    for (int kb = k0; kb < k1; kb += 16) {
        int rem = k1 - kb;
        int idx = (l < rem) ? csr[kb + l] : N;
        unsigned uu[16];
#pragma unroll
        for (int t = 0; t < 16; ++t) {
            int s = __shfl(idx, gw4 + t);
            uu[t] = hs8[(unsigned)((s << 4) | l)];
        }
#pragma unroll
        for (int t = 0; t < 16; t += 4) {
            floatx2 q0 = __builtin_amdgcn_cvt_pk_f32_fp8((int)uu[t + 0], false);
            floatx2 q1 = __builtin_amdgcn_cvt_pk_f32_fp8((int)uu[t + 0], true);
            floatx2 q2 = __builtin_amdgcn_cvt_pk_f32_fp8((int)uu[t + 1], false);
            floatx2 q3 = __builtin_amdgcn_cvt_pk_f32_fp8((int)uu[t + 1], true);
            floatx2 q4 = __builtin_amdgcn_cvt_pk_f32_fp8((int)uu[t + 2], false);
            floatx2 q5 = __builtin_amdgcn_cvt_pk_f32_fp8((int)uu[t + 2], true);
            floatx2 q6 = __builtin_amdgcn_cvt_pk_f32_fp8((int)uu[t + 3], false);
            floatx2 q7 = __builtin_amdgcn_cvt_pk_f32_fp8((int)uu[t + 3], true);
            a0.x += q0.x; a0.y += q0.y; a0.z += q1.x; a0.w += q1.y;
            a1.x += q2.x; a1.y += q2.y; a1.z += q3.x; a1.w += q3.y;
            a2.x += q4.x; a2.y += q4.y; a2.z += q5.x; a2.w += q5.y;
            a3.x += q6.x; a3.y += q6.y; a3.z += q7.x; a3.w += q7.y;
        }
    }
    return make_float4(a0.x + a1.x + a2.x + a3.x,
                       a0.y + a1.y + a2.y + a3.y,
                       a0.z + a1.z + a2.z + a3.z,
                       a0.w + a1.w + a2.w + a3.w);
}

// ---------------- fused gather + MFMA GEMM (layer 1 -> hs2 fp8 directly) ----------------
// block = 256 threads = 16 nodes. gathered row relu'd into fp16 LDS tile, MFMA vs W2
// fragments (built from global, no W LDS), fp32 epilogue transpose via Os, fp8 out.

__global__ __launch_bounds__(256) void k_gather_gemm(const unsigned int* __restrict__ hs8,
                                                     const int* __restrict__ csr,
                                                     const int* __restrict__ off,
                                                     const float* __restrict__ dinv,
                                                     const float* __restrict__ bias,
                                                     const float* __restrict__ W,
                                                     unsigned int* __restrict__ hs_out,
                                                     int N) {
    __shared__ _Float16 Xs[16 * 72];
    __shared__ float Os[16 * 68];
    int tid = threadIdx.x;
    int r = tid >> 4, l = tid & 15;
    int lane = tid & 63, w = tid >> 6;
    int m = lane & 15, g = lane >> 4;
    int gw4 = (r & 3) << 4;
    int v = blockIdx.x * 16 + r;

    // B fragments first (global-load latency overlaps the gather)
    f16x8 B0, B1;
    {
        int n = (w << 4) + m;
        const float* wp = W + (g << 3) * 64 + n;
#pragma unroll
        for (int j = 0; j < 8; ++j) B0[j] = (_Float16)wp[j * 64];
        wp += 32 * 64;
#pragma unroll
        for (int j = 0; j < 8; ++j) B1[j] = (_Float16)wp[j * 64];
    }
    if (blockIdx.x == 0 && tid < 16)
        hs_out[(size_t)N * 16 + tid] = 0u;               // zero pad row for gather2

    float dv = 0.f;
    float4 h = make_float4(0.f, 0.f, 0.f, 0.f);
    if (v < N) {
        dv = dinv[v];
        float4 bv = ((const float4*)bias)[l];
        float4 acc = gather_rows(hs8, csr, off[v], off[v + 1], v, l, gw4, N);
        h.x = fmaxf(acc.x * dv + bv.x, 0.f);
        h.y = fmaxf(acc.y * dv + bv.y, 0.f);
        h.z = fmaxf(acc.z * dv + bv.z, 0.f);
        h.w = fmaxf(acc.w * dv + bv.w, 0.f);
    }
    {
        f16x4 hv;
        hv[0] = (_Float16)h.x; hv[1] = (_Float16)h.y;
        hv[2] = (_Float16)h.z; hv[3] = (_Float16)h.w;
        *(f16x4*)(Xs + r * 72 + (l << 2)) = hv;
    }
    __syncthreads();

    f16x8 A0 = *(const f16x8*)(Xs + m * 72 + (g << 3));
    f16x8 A1 = *(const f16x8*)(Xs + m * 72 + 32 + (g << 3));
    f32x4 acc2 = {0.f, 0.f, 0.f, 0.f};
    acc2 = __builtin_amdgcn_mfma_f32_16x16x32_f16(A0, B0, acc2, 0, 0, 0);
    acc2 = __builtin_amdgcn_mfma_f32_16x16x32_f16(A1, B1, acc2, 0, 0, 0);
#pragma unroll
    for (int j = 0; j < 4; ++j)
        Os[((g << 2) + j) * 68 + (w << 4) + m] = acc2[j];
    __syncthreads();

    if (v < N) {
        float4 o = *(const float4*)(Os + r * 68 + (l << 2));
        int p = 0;
        p = __builtin_amdgcn_cvt_pk_fp8_f32(o.x * dv, o.y * dv, p, false);
        p = __builtin_amdgcn_cvt_pk_fp8_f32(o.z * dv, o.w * dv, p, true);
        hs_out[(size_t)v * 16 + l] = (unsigned int)p;
    }
}

// ---------------- fused gather (layer 2) + mean-pool: atomics into out ----------------
// block = 16 nodes; batch sorted -> 1-2 graph segments per block. Each group computes
// relu(acc*dinv+b2)/count[g]; segment leaders reduce over LDS and atomicAdd into out.

__global__ __launch_bounds__(256) void k_gather_pool(const unsigned int* __restrict__ hs8,
                                                     const int* __restrict__ csr,
                                                     const int* __restrict__ off,
                                                     const float* __restrict__ dinv,
                                                     const float* __restrict__ bias,
                                                     const int* __restrict__ batch,
                                                     const int* __restrict__ goff,
                                                     float* __restrict__ out, int N) {
    __shared__ float vals[16][68];
    __shared__ int gid[16];
    int tid = threadIdx.x;
    int r = tid >> 4, l = tid & 15;
    int gw4 = (r & 3) << 4;
    int v = blockIdx.x * 16 + r;

    float4 val = make_float4(0.f, 0.f, 0.f, 0.f);
    int g = -1;
    if (v < N) {
        g = batch[v];
        float dv = dinv[v];
        float4 bv = ((const float4*)bias)[l];
        float4 acc = gather_rows(hs8, csr, off[v], off[v + 1], v, l, gw4, N);
        float inv = 1.0f / (float)(goff[g + 1] - goff[g]);
        val.x = fmaxf(acc.x * dv + bv.x, 0.f) * inv;
        val.y = fmaxf(acc.y * dv + bv.y, 0.f) * inv;
        val.z = fmaxf(acc.z * dv + bv.z, 0.f) * inv;
        val.w = fmaxf(acc.w * dv + bv.w, 0.f) * inv;
    }
    *(float4*)(&vals[r][l << 2]) = val;
    if (l == 0) gid[r] = g;
    __syncthreads();

    if (v < N) {
        bool leader = (r == 0) || (gid[r - 1] != g);
        if (leader) {
            float4 sacc = val;
            for (int rr = r + 1; rr < 16 && gid[rr] == g; ++rr) {
                float4 t = *(const float4*)(&vals[rr][l << 2]);
                sacc.x += t.x; sacc.y += t.y; sacc.z += t.z; sacc.w += t.w;
            }
            float* op = out + (size_t)g * DIM + (l << 2);
            atomicAdd(op + 0, sacc.x);
            atomicAdd(op + 1, sacc.y);
            atomicAdd(op + 2, sacc.z);
            atomicAdd(op + 3, sacc.w);
        }
    }
}

// ---------------- launch ----------------

static inline int cdiv(int a, int b) { return (a + b - 1) / b; }

extern "C" void kernel_launch(void* const* d_in, const int* in_sizes, int n_in,
                              void* d_out, int out_size, void* d_ws, size_t ws_size,
                              hipStream_t stream) {
    const float* x   = (const float*)d_in[0];
    const float* W1  = (const float*)d_in[1];
    const float* b1  = (const float*)d_in[2];
    const float* W2  = (const float*)d_in[3];
    const float* b2  = (const float*)d_in[4];
    const int*   ei  = (const int*)d_in[5];
    const int*   bat = (const int*)d_in[6];

    const int N = in_sizes[0] / DIM;
    const int E = in_sizes[5] / 2;
    const int G = out_size / DIM;
    const int NB = cdiv(N, BINSZ);           // <= MAXBINS
    const int* src = ei;
    const int* dst = ei + E;
    float* out = (float*)d_out;

    // workspace: hs1 | hs2 | dinv | off | goff | bintot | binoff | bincur | csr
    // bkt aliases hs1 (dead before gemm1 writes hs1).
    __half* hs1    = (__half*)d_ws;                         // (N+1)*64 h region (fp8 uses half)
    __half* hs2    = hs1 + (size_t)(N + 1) * DIM;           // (N+1)*64 h region
    float*  dinv   = (float*)(hs2 + (size_t)(N + 1) * DIM); // N f
    int*    off    = (int*)(dinv + N);                      // N+1 i
    int*    goff   = off + (N + 1);                         // G+1 i
    int*    bintot = goff + (G + 1);                        // MAXBINS i
    int*    binoff = bintot + MAXBINS;                      // MAXBINS+1 i
    int*    bincur = binoff + (MAXBINS + 1);                // MAXBINS i
    int*    csr    = bincur + MAXBINS;                      // E i
    int*    bkt    = (int*)hs1;                             // E i (aliased)

    k_zero<<<256, 256, 0, stream>>>(bintot, out, NB, G * DIM);
    k_hist2<<<PB, 256, 0, stream>>>(dst, bintot, E, NB);
    k_scan782<<<1, 256, 0, stream>>>(bintot, binoff, bincur, NB, E);
    k_bucket2<<<PB, 256, 0, stream>>>(src, dst, bincur, bkt, E, NB);
    k_binsort<<<NB, 256, 0, stream>>>(bkt, binoff, csr, off, dinv, bat, goff, N, G, E, NB);

    // layer 1 transform: hs1 = (x @ W1) * dinv (fp8 e4m3), MFMA
    k_gemm<<<cdiv(N + 1, 16), 256, 0, stream>>>(x, W1, dinv, (unsigned int*)hs1, N);

    // fused: agg1 = gather(hs1)+b1 ; hs2 = (relu(agg1) @ W2) * dinv (fp8), MFMA
    k_gather_gemm<<<cdiv(N, 16), 256, 0, stream>>>((const unsigned int*)hs1, csr, off,
                                                   dinv, b1, W2, (unsigned int*)hs2, N);

    // fused: layer 2 gather + bias + relu + mean-pool (atomics into out)
    k_gather_pool<<<cdiv(N, 16), 256, 0, stream>>>((const unsigned int*)hs2, csr, off,
                                                   dinv, b2, bat, goff, out, N);
}